// Round 7
// baseline (33.852 us; speedup 1.0000x reference)
//
#include <hip/hip_runtime.h>

// LengthRegulator fused single-kernel: B=32, S=512, D=512, T(max_mel)=2048
// out = [padded (B*T*D f32)] ++ [d (B*S, written as float values)]
//
// Each 512-thread block owns FPB=128 consecutive output frames of one batch.
// Prologue: durations load -> shfl scan -> barrier -> per-thread SCATTER of
// token id into the block's stok[] window -> barrier -> row copies.
// R6 single-variable change: plain stores instead of nontemporal (fills
// sustain 6.9 TB/s through the L2 write path; A/B the store mode).

#define BB 32
#define SS 512
#define DD 512
#define TT 2048
#define SLOWDOWN 0.5f
#define FPB 128           // frames per block; TT/FPB = 16 chunks per batch

using f32x4 = __attribute__((ext_vector_type(4))) float;

__global__ __launch_bounds__(512)
void lr_fused(const float* __restrict__ durations,
              const float* __restrict__ seq,
              float* __restrict__ out,
              float* __restrict__ d_out_tail) {
    const int blk   = blockIdx.x;
    const int b     = blk >> 4;           // blk / (TT/FPB)
    const int chunk = blk & 15;
    const int tbase = chunk * FPB;        // first frame this block writes
    const int tid   = threadIdx.x;        // 0..511 == token index
    const int lane  = tid & 63;
    const int wv    = tid >> 6;           // 0..7

    __shared__ int stok[FPB];
    __shared__ int wtot[8];

    if (tid < FPB) stok[tid] = SS;        // pad sentinel; published by barrier 1

    // ---- duration + inclusive scan for batch b (1 token per thread) ----
    const float dur = durations[b * SS + tid];
    const int di = (int)fmaxf(dur + SLOWDOWN, 1.0f);   // trunc == floor; di in [1,8]

    int v = di;                           // wave inclusive scan (6 shuffle steps)
#pragma unroll
    for (int off = 1; off < 64; off <<= 1) {
        int n = __shfl_up(v, off);
        if (lane >= off) v += n;
    }
    if (lane == 63) wtot[wv] = v;

    if (chunk == 0)                       // one block per batch emits d
        d_out_tail[b * SS + tid] = (float)di;

    __syncthreads();                      // barrier 1: wtot + stok init visible
    int woff = 0;
#pragma unroll
    for (int w = 0; w < 7; ++w) woff += (w < wv) ? wtot[w] : 0;

    const int csum  = v + woff;           // inclusive end offset of token tid
    // ---- scatter: frames [csum-di, csum) ∩ [tbase, tbase+FPB) -> token tid ----
    {
        int f0 = csum - di; if (f0 < tbase) f0 = tbase;
        int f1 = csum;      if (f1 > tbase + FPB) f1 = tbase + FPB;
        for (int f = f0; f < f1; ++f) stok[f - tbase] = tid;   // disjoint addrs
    }
    __syncthreads();                      // barrier 2: stok ready

    // ---- row copies: 4 frames in parallel, 128 f32x4 lanes per row ----
    const int sub = tid >> 7;             // 0..3: which frame of the quad
    const int l   = tid & 127;
    const f32x4* sbase = reinterpret_cast<const f32x4*>(seq + (size_t)b * SS * DD) + l;
    f32x4* obase = reinterpret_cast<f32x4*>(out + ((size_t)b * TT + tbase) * DD) + l;

#pragma unroll 8
    for (int p = 0; p < FPB / 4; ++p) {
        const int fi  = p * 4 + sub;
        const int tok = stok[fi];                   // LDS broadcast
        const int tc  = (tok < SS) ? tok : (SS - 1);
        f32x4 r = sbase[(size_t)tc * (DD / 4)];     // branchless: always load
        if (tok >= SS) r = (f32x4){0.f, 0.f, 0.f, 0.f};
        obase[(size_t)fi * (DD / 4)] = r;           // plain store (R6 A/B vs nt)
    }
}

extern "C" void kernel_launch(void* const* d_in, const int* in_sizes, int n_in,
                              void* d_out, int out_size, void* d_ws, size_t ws_size,
                              hipStream_t stream) {
    const float* sequences = (const float*)d_in[0];   // [B,S,D] f32
    const float* durations = (const float*)d_in[1];   // [B,S]   f32
    // d_in[2] = max_mel_length scalar (fixed 2048, compile-time)

    float* out        = (float*)d_out;
    float* d_out_tail = out + (size_t)BB * TT * DD;   // second output: d as floats

    lr_fused<<<BB * (TT / FPB), 512, 0, stream>>>(durations, sequences, out, d_out_tail);
}

// Round 8
// 30.006 us; speedup vs baseline: 1.1282x; 1.1282x over previous
//
#include <hip/hip_runtime.h>

// LengthRegulator fused single-kernel: B=32, S=512, D=512, T(max_mel)=2048
// out = [padded (B*T*D f32)] ++ [d (B*S, written as float values)]
//
// R7 = exact revert to R5 (best: 29.87 us). R6's A/B proved nontemporal
// stores are worth ~4 us: plain stores push 134 MB of streaming writes
// through L2, evicting the seq read rows (33.9 us). Keep nt stores.
//
// Each 512-thread block owns FPB=128 consecutive output frames of one batch.
// Prologue: durations load -> shfl scan -> barrier -> per-thread SCATTER of
// token id into the block's stok[] window (each thread knows its own
// [csum-di, csum) span; di<=8) -> barrier -> row copies with nt stores.

#define BB 32
#define SS 512
#define DD 512
#define TT 2048
#define SLOWDOWN 0.5f
#define FPB 128           // frames per block; TT/FPB = 16 chunks per batch

using f32x4 = __attribute__((ext_vector_type(4))) float;

__global__ __launch_bounds__(512)
void lr_fused(const float* __restrict__ durations,
              const float* __restrict__ seq,
              float* __restrict__ out,
              float* __restrict__ d_out_tail) {
    const int blk   = blockIdx.x;
    const int b     = blk >> 4;           // blk / (TT/FPB)
    const int chunk = blk & 15;
    const int tbase = chunk * FPB;        // first frame this block writes
    const int tid   = threadIdx.x;        // 0..511 == token index
    const int lane  = tid & 63;
    const int wv    = tid >> 6;           // 0..7

    __shared__ int stok[FPB];
    __shared__ int wtot[8];

    if (tid < FPB) stok[tid] = SS;        // pad sentinel; published by barrier 1

    // ---- duration + inclusive scan for batch b (1 token per thread) ----
    const float dur = durations[b * SS + tid];
    const int di = (int)fmaxf(dur + SLOWDOWN, 1.0f);   // trunc == floor; di in [1,8]

    int v = di;                           // wave inclusive scan (6 shuffle steps)
#pragma unroll
    for (int off = 1; off < 64; off <<= 1) {
        int n = __shfl_up(v, off);
        if (lane >= off) v += n;
    }
    if (lane == 63) wtot[wv] = v;

    if (chunk == 0)                       // one block per batch emits d
        d_out_tail[b * SS + tid] = (float)di;

    __syncthreads();                      // barrier 1: wtot + stok init visible
    int woff = 0;
#pragma unroll
    for (int w = 0; w < 7; ++w) woff += (w < wv) ? wtot[w] : 0;

    const int csum  = v + woff;           // inclusive end offset of token tid
    // ---- scatter: frames [csum-di, csum) ∩ [tbase, tbase+FPB) -> token tid ----
    {
        int f0 = csum - di; if (f0 < tbase) f0 = tbase;
        int f1 = csum;      if (f1 > tbase + FPB) f1 = tbase + FPB;
        for (int f = f0; f < f1; ++f) stok[f - tbase] = tid;   // disjoint addrs
    }
    __syncthreads();                      // barrier 2: stok ready

    // ---- row copies: 4 frames in parallel, 128 f32x4 lanes per row ----
    const int sub = tid >> 7;             // 0..3: which frame of the quad
    const int l   = tid & 127;
    const f32x4* sbase = reinterpret_cast<const f32x4*>(seq + (size_t)b * SS * DD) + l;
    f32x4* obase = reinterpret_cast<f32x4*>(out + ((size_t)b * TT + tbase) * DD) + l;

#pragma unroll 8
    for (int p = 0; p < FPB / 4; ++p) {
        const int fi  = p * 4 + sub;
        const int tok = stok[fi];                   // LDS broadcast
        const int tc  = (tok < SS) ? tok : (SS - 1);
        f32x4 r = sbase[(size_t)tc * (DD / 4)];     // branchless: always load
        if (tok >= SS) r = (f32x4){0.f, 0.f, 0.f, 0.f};
        __builtin_nontemporal_store(r, obase + (size_t)fi * (DD / 4));
    }
}

extern "C" void kernel_launch(void* const* d_in, const int* in_sizes, int n_in,
                              void* d_out, int out_size, void* d_ws, size_t ws_size,
                              hipStream_t stream) {
    const float* sequences = (const float*)d_in[0];   // [B,S,D] f32
    const float* durations = (const float*)d_in[1];   // [B,S]   f32
    // d_in[2] = max_mel_length scalar (fixed 2048, compile-time)

    float* out        = (float*)d_out;
    float* d_out_tail = out + (size_t)BB * TT * DD;   // second output: d as floats

    lr_fused<<<BB * (TT / FPB), 512, 0, stream>>>(durations, sequences, out, d_out_tail);
}